// Round 4
// baseline (155.730 us; speedup 1.0000x reference)
//
#include <hip/hip_runtime.h>
#include <math.h>
#include <stdint.h>

#define BB 4
#define CC 129
#define HH 512
#define WW 512
#define HWSZ (HH*WW)
#define JJ 512
#define KK 1024
#define NKP (JJ+KK)
#define RAD 7
#define TSX 64
#define TSY 32
#define HLX (TSX + 2*RAD)   // 78
#define HLY (TSY + 2*RAD)   // 46
#define CAP 8192
#define NL 2048
#define NMS_THRESH 0.99f
#define GRID 512            // 4 batches * 8 xtiles * 16 ytiles
#define RANKBLKS 128        // 32 per batch
#define KPB 12              // keypoints per block in desc phase (512*12 = 6144)

// ws layout (bytes): [0..16) cnt[4] ; [64..72) bar1,bar2 ; candK ; sortK
static const size_t OFF_CNT   = 0;
static const size_t OFF_BAR   = 64;
static const size_t OFF_CANDK = 256;
static const size_t OFF_SORTK = OFF_CANDK + (size_t)BB*CAP*8;

// Device-scope grid barrier: all GRID blocks are co-resident by construction
// (launch_bounds(256,4) -> VGPR<=128 -> >=4 blocks/CU -> capacity >=1024 > 512;
// LDS 26.1KB -> 6/CU). Release on arrive publishes this block's prior stores
// (each wave's stores completed at its __syncthreads); acquire after release
// spin invalidates L1/L2 so post-barrier plain loads see remote writes.
__device__ __forceinline__ void gridbar(uint32_t* bar) {
    __syncthreads();
    if (threadIdx.x == 0) {
        __hip_atomic_fetch_add(bar, 1u, __ATOMIC_RELEASE, __HIP_MEMORY_SCOPE_AGENT);
        while (__hip_atomic_load(bar, __ATOMIC_RELAXED, __HIP_MEMORY_SCOPE_AGENT) < (uint32_t)GRID)
            __builtin_amdgcn_s_sleep(2);
        (void)__hip_atomic_load(bar, __ATOMIC_ACQUIRE, __HIP_MEMORY_SCOPE_AGENT);
    }
    __syncthreads();
}

__global__ __launch_bounds__(256, 4)
void k_fused(const float* __restrict__ in, const int* __restrict__ juncs,
             int* __restrict__ cnt, uint32_t* __restrict__ bars,
             uint64_t* __restrict__ candK, uint64_t* __restrict__ sortK,
             float* __restrict__ out_kp, float* __restrict__ out_desc,
             float* __restrict__ out_sc) {
    __shared__ union {
        struct { float s[HLY*HLX]; float hm[HLY*TSX]; } a;  // 14352 + 11776 B
        struct { uint64_t sk[NL]; int part[4][64]; } r;     // 16384 + 1024 B
    } u;
    const int tid = threadIdx.x;
    const int blk = blockIdx.x;

    // ---------------- Phase A: tiled 15x15 NMS + candidate collection -------
    if (blk < 16) sortK[blk*256 + tid] = 0xFF800000FFFFFFFFULL;  // -inf sentinel

    {
        int b = blk >> 7;             // 128 tiles per batch
        int t = blk & 127;
        int ty = t >> 3, tx = t & 7;
        int bx = tx*TSX - RAD, by = ty*TSY - RAD;
        const float* heat = in + (size_t)b * CC * HWSZ;
        for (int i = tid; i < HLY*HLX; i += 256) {
            int r = i / HLX, c = i - r*HLX;
            int gy = by + r, gx = bx + c;
            float val = (gy >= 0 && gy < HH && gx >= 0 && gx < WW)
                          ? heat[gy*WW + gx] : -INFINITY;
            u.a.s[i] = val;
        }
        __syncthreads();
        for (int i = tid; i < HLY*TSX; i += 256) {   // horizontal 15-max
            int r = i >> 6, c = i & 63;
            const float* sp = u.a.s + r*HLX + c;
            float m = sp[0];
            #pragma unroll
            for (int k = 1; k < 15; ++k) m = fmaxf(m, sp[k]);
            u.a.hm[i] = m;
        }
        __syncthreads();
        for (int i = tid; i < TSY*TSX; i += 256) {   // vertical 15-max + collect
            int r = i >> 6, c = i & 63;
            float v = u.a.s[(r+RAD)*HLX + (c+RAD)];
            if (v > NMS_THRESH) {
                const float* hp = u.a.hm + r*TSX + c;
                float m = hp[0];
                #pragma unroll
                for (int k = 1; k < 15; ++k) m = fmaxf(m, hp[k*TSX]);
                if (v == m) {                         // exact fp equality, as ref
                    int gy = ty*TSY + r, gx = tx*TSX + c;
                    int pos = atomicAdd(&cnt[b], 1);
                    if (pos < CAP) {
                        uint32_t idx = (uint32_t)(gy*WW + gx);
                        candK[b*CAP + pos] =
                            ((uint64_t)__float_as_uint(v) << 32) | (uint32_t)(~idx);
                    }
                }
            }
        }
    }

    gridbar(&bars[0]);

    // ---------------- Phase B: exact top-K rank counting (128 blocks) -------
    if (blk < RANKBLKS) {
        int b = blk >> 5;
        int chunk = blk & 31;
        int n = cnt[b]; if (n > NL) n = NL;
        int i0 = chunk * 64;
        if (i0 < n) {                    // block-uniform
            const uint64_t* ck = candK + b*CAP;
            for (int j = tid; j < n; j += 256) u.r.sk[j] = ck[j];
            __syncthreads();
            int w = tid >> 6, l = tid & 63;
            int i = i0 + l;
            uint64_t key = (i < n) ? u.r.sk[i] : ~0ULL;
            int jc = (n + 3) >> 2;
            int j0 = w*jc, j1 = j0 + jc; if (j1 > n) j1 = n;
            int r = 0;
            for (int j = j0; j < j1; ++j) r += (u.r.sk[j] > key);
            u.r.part[w][l] = r;
            __syncthreads();
            if (tid < 64 && i0 + tid < n) {
                int rank = u.r.part[0][tid] + u.r.part[1][tid]
                         + u.r.part[2][tid] + u.r.part[3][tid];
                if (rank < KK) sortK[b*KK + rank] = u.r.sk[i0 + tid];
            }
        }
    }

    gridbar(&bars[1]);

    // ---------------- Phase C: finalize + descriptor gather -----------------
    // 12 kps per block; one 32-lane half-wave per kp, 4 channels per lane.
    {
        int hw = tid >> 5;              // 0..7
        int l  = tid & 31;
        for (int q = hw; q < KPB; q += 8) {
            int g = blk*KPB + q;        // 0..6143
            int b = g / NKP, k = g - b*NKP;
            int kx, ky; float sc;
            if (k < JJ) {
                kx = juncs[(b*JJ + k)*2 + 0];
                ky = juncs[(b*JJ + k)*2 + 1];
                sc = 1.0f;
            } else {
                uint64_t key  = sortK[b*KK + (k - JJ)];
                uint64_t key0 = sortK[b*KK];
                float v  = __uint_as_float((uint32_t)(key  >> 32));
                float v0 = __uint_as_float((uint32_t)(key0 >> 32));
                int rr = (int)(~(uint32_t)key);
                kx = rr & (WW-1); ky = rr >> 9;
                sc = v / v0;
            }
            int fi = ky*WW + kx;
            const float* fp = in + (size_t)b*CC*HWSZ + HWSZ + fi;
            float a0 = fp[(size_t)(l      )*HWSZ];
            float a1 = fp[(size_t)(l + 32 )*HWSZ];
            float a2 = fp[(size_t)(l + 64 )*HWSZ];
            float a3 = fp[(size_t)(l + 96 )*HWSZ];
            float s = a0*a0 + a1*a1 + a2*a2 + a3*a3;
            for (int m = 1; m < 32; m <<= 1) s += __shfl_xor(s, m, 32);
            float nrm = fmaxf(sqrtf(s), 1e-12f);
            float* dp = out_desc + (size_t)g * 128;
            dp[l]      = a0 / nrm;
            dp[l + 32] = a1 / nrm;
            dp[l + 64] = a2 / nrm;
            dp[l + 96] = a3 / nrm;
            if (l == 0) {
                out_kp[2*g]     = (float)kx;
                out_kp[2*g + 1] = (float)ky;
                out_sc[g]       = sc;
            }
        }
    }
}

extern "C" void kernel_launch(void* const* d_in, const int* in_sizes, int n_in,
                              void* d_out, int out_size, void* d_ws, size_t ws_size,
                              hipStream_t stream) {
    const float* in  = (const float*)d_in[0];
    const int* juncs = (const int*)d_in[1];
    float* out       = (float*)d_out;

    char* ws = (char*)d_ws;
    int*      cnt   = (int*)(ws + OFF_CNT);
    uint32_t* bars  = (uint32_t*)(ws + OFF_BAR);
    uint64_t* candK = (uint64_t*)(ws + OFF_CANDK);
    uint64_t* sortK = (uint64_t*)(ws + OFF_SORTK);

    float* out_kp   = out;                                          // BB*NKP*2
    float* out_desc = out + (size_t)BB*NKP*2;                       // BB*NKP*128
    float* out_sc   = out + (size_t)BB*NKP*2 + (size_t)BB*NKP*128;  // BB*NKP

    // zero counters + barrier slots every launch (replay-deterministic)
    hipMemsetAsync(d_ws, 0, 128, stream);
    k_fused<<<GRID, 256, 0, stream>>>(in, juncs, cnt, bars, candK, sortK,
                                      out_kp, out_desc, out_sc);
}

// Round 5
// 99.006 us; speedup vs baseline: 1.5729x; 1.5729x over previous
//
#include <hip/hip_runtime.h>
#include <math.h>
#include <stdint.h>

#define BB 4
#define CC 129
#define HH 512
#define WW 512
#define HWSZ (HH*WW)
#define JJ 512
#define KK 1024
#define NKP (JJ+KK)
#define RAD 7
#define TS 32
#define HL (TS + 2*RAD)     // 46
#define CAP 8192
#define NL 2048
#define NMS_THRESH 0.99f
#define NMSBLKS 1024        // 4 batches * 16*16 tiles of 32x32
#define JDBLKS 256          // 2048 junc kps, 8 per block
#define RANKBLKS 128        // 32 per batch

// ws layout (bytes)
static const size_t OFF_CNT   = 0;                            // BB ints
static const size_t OFF_CANDK = 256;                          // BB*CAP*8
static const size_t OFF_SORTK = OFF_CANDK + (size_t)BB*CAP*8; // BB*KK*8

// Kernel 1: tiled 15x15 NMS (separable, all in LDS) + candidate collect.
// Extra blocks (blk >= NMSBLKS) do the junction descriptors concurrently —
// they depend only on `juncs`, so their scattered gather latency hides under
// the NMS blocks' compute. First 16 blocks also init sortK sentinels.
__global__ __launch_bounds__(256)
void k_nms(const float* __restrict__ in, const int* __restrict__ juncs,
           int* __restrict__ cnt, uint64_t* __restrict__ candK,
           uint64_t* __restrict__ sortK,
           float* __restrict__ out_kp, float* __restrict__ out_desc,
           float* __restrict__ out_sc) {
    __shared__ float s[HL*HL];      // 2116 floats
    __shared__ float hm[HL*TS];     // 1472 floats
    const int tid = threadIdx.x;
    const int blk = blockIdx.x;

    if (blk < 16) sortK[blk*256 + tid] = 0xFF800000FFFFFFFFULL;  // -inf sentinel

    if (blk < NMSBLKS) {
        int b = blk >> 8;                 // 256 tiles per batch
        int t = blk & 255;
        int ty = t >> 4, tx = t & 15;
        int by = ty*TS - RAD, bx = tx*TS - RAD;
        const float* heat = in + (size_t)b * CC * HWSZ;
        for (int i = tid; i < HL*HL; i += 256) {
            int r = i / HL, c = i - r*HL;
            int gy = by + r, gx = bx + c;
            s[i] = (gy >= 0 && gy < HH && gx >= 0 && gx < WW)
                     ? heat[gy*WW + gx] : -INFINITY;
        }
        __syncthreads();
        for (int i = tid; i < HL*TS; i += 256) {    // horizontal 15-max
            int r = i >> 5, c = i & 31;
            const float* sp = s + r*HL + c;
            float m = sp[0];
            #pragma unroll
            for (int k = 1; k < 15; ++k) m = fmaxf(m, sp[k]);
            hm[i] = m;
        }
        __syncthreads();
        for (int i = tid; i < TS*TS; i += 256) {    // vertical 15-max + collect
            int r = i >> 5, c = i & 31;
            float v = s[(r+RAD)*HL + (c+RAD)];
            if (v > NMS_THRESH) {
                const float* hp = hm + r*TS + c;
                float m = hp[0];
                #pragma unroll
                for (int k = 1; k < 15; ++k) m = fmaxf(m, hp[k*TS]);
                if (v == m) {                        // exact fp equality, as ref
                    int gy = ty*TS + r, gx = tx*TS + c;
                    int pos = atomicAdd(&cnt[b], 1);
                    if (pos < CAP) {
                        uint32_t idx = (uint32_t)(gy*WW + gx);
                        candK[b*CAP + pos] =
                            ((uint64_t)__float_as_uint(v) << 32) | (uint32_t)(~idx);
                    }
                }
            }
        }
    } else {
        // Junction descriptors: 8 kps/block, one 32-lane group per kp,
        // 4 channels per lane (4 independent loads in flight).
        int jb = blk - NMSBLKS;
        int g2 = tid >> 5, l = tid & 31;
        int j  = jb*8 + g2;               // 0..2047
        int b  = j >> 9, k = j & 511;
        int kx = juncs[(b*JJ + k)*2 + 0];
        int ky = juncs[(b*JJ + k)*2 + 1];
        int fi = ky*WW + kx;
        const float* fp = in + (size_t)b*CC*HWSZ + HWSZ + fi;
        float a0 = fp[(size_t)(l      )*HWSZ];
        float a1 = fp[(size_t)(l + 32 )*HWSZ];
        float a2 = fp[(size_t)(l + 64 )*HWSZ];
        float a3 = fp[(size_t)(l + 96 )*HWSZ];
        float sq = a0*a0 + a1*a1 + a2*a2 + a3*a3;
        for (int m = 1; m < 32; m <<= 1) sq += __shfl_xor(sq, m, 32);
        float nrm = fmaxf(sqrtf(sq), 1e-12f);
        int go = b*NKP + k;
        float* dp = out_desc + (size_t)go * 128;
        dp[l]      = a0 / nrm;
        dp[l + 32] = a1 / nrm;
        dp[l + 64] = a2 / nrm;
        dp[l + 96] = a3 / nrm;
        if (l == 0) {
            out_kp[2*go]     = (float)kx;
            out_kp[2*go + 1] = (float)ky;
            out_sc[go]       = 1.0f;
        }
    }
}

// Kernel 2: exact top-K rank counting on packed keys (value<<32 | ~idx).
// rank_i = #{j : key_j > key_i} reproduces top_k (desc, asc-idx ties)
// deterministically regardless of atomic append order.
__global__ __launch_bounds__(256)
void k_rank(const int* __restrict__ cnt, const uint64_t* __restrict__ candK,
            uint64_t* __restrict__ sortK) {
    __shared__ uint64_t sk[NL];
    __shared__ int part[4][64];
    int b   = blockIdx.x >> 5;
    int blk = blockIdx.x & 31;
    int n = cnt[b]; if (n > NL) n = NL;
    int i0 = blk * 64;
    if (i0 >= n) return;                  // block-uniform
    const uint64_t* ck = candK + b*CAP;
    for (int j = threadIdx.x; j < n; j += 256) sk[j] = ck[j];
    __syncthreads();
    int w = threadIdx.x >> 6, l = threadIdx.x & 63;
    int i = i0 + l;
    uint64_t key = (i < n) ? sk[i] : ~0ULL;
    int jc = (n + 3) >> 2;
    int j0 = w*jc, j1 = j0 + jc; if (j1 > n) j1 = n;
    int r = 0;
    for (int j = j0; j < j1; ++j) r += (sk[j] > key);
    part[w][l] = r;
    __syncthreads();
    if (threadIdx.x < 64 && i0 + threadIdx.x < n) {
        int rank = part[0][threadIdx.x] + part[1][threadIdx.x]
                 + part[2][threadIdx.x] + part[3][threadIdx.x];
        if (rank < KK) sortK[b*KK + rank] = sk[i0 + threadIdx.x];
    }
}

// Kernel 3: finalize + descriptor gather for the 4096 NMS keypoints.
__global__ __launch_bounds__(256)
void k_desc(const float* __restrict__ in, const uint64_t* __restrict__ sortK,
            float* __restrict__ out_kp, float* __restrict__ out_desc,
            float* __restrict__ out_sc) {
    int g = blockIdx.x*8 + (threadIdx.x >> 5);   // 0..4095
    int l = threadIdx.x & 31;
    int b = g >> 10, k = g & 1023;
    uint64_t key  = sortK[b*KK + k];
    uint64_t key0 = sortK[b*KK];
    float v  = __uint_as_float((uint32_t)(key  >> 32));
    float v0 = __uint_as_float((uint32_t)(key0 >> 32));
    int rr = (int)(~(uint32_t)key);
    int kx = rr & (WW-1), ky = rr >> 9;
    float sc = v / v0;
    int fi = ky*WW + kx;
    const float* fp = in + (size_t)b*CC*HWSZ + HWSZ + fi;
    float a0 = fp[(size_t)(l      )*HWSZ];
    float a1 = fp[(size_t)(l + 32 )*HWSZ];
    float a2 = fp[(size_t)(l + 64 )*HWSZ];
    float a3 = fp[(size_t)(l + 96 )*HWSZ];
    float sq = a0*a0 + a1*a1 + a2*a2 + a3*a3;
    for (int m = 1; m < 32; m <<= 1) sq += __shfl_xor(sq, m, 32);
    float nrm = fmaxf(sqrtf(sq), 1e-12f);
    int go = b*NKP + JJ + k;
    float* dp = out_desc + (size_t)go * 128;
    dp[l]      = a0 / nrm;
    dp[l + 32] = a1 / nrm;
    dp[l + 64] = a2 / nrm;
    dp[l + 96] = a3 / nrm;
    if (l == 0) {
        out_kp[2*go]     = (float)kx;
        out_kp[2*go + 1] = (float)ky;
        out_sc[go]       = sc;
    }
}

extern "C" void kernel_launch(void* const* d_in, const int* in_sizes, int n_in,
                              void* d_out, int out_size, void* d_ws, size_t ws_size,
                              hipStream_t stream) {
    const float* in  = (const float*)d_in[0];
    const int* juncs = (const int*)d_in[1];
    float* out       = (float*)d_out;

    char* ws = (char*)d_ws;
    int*      cnt   = (int*)(ws + OFF_CNT);
    uint64_t* candK = (uint64_t*)(ws + OFF_CANDK);
    uint64_t* sortK = (uint64_t*)(ws + OFF_SORTK);

    float* out_kp   = out;                                          // BB*NKP*2
    float* out_desc = out + (size_t)BB*NKP*2;                       // BB*NKP*128
    float* out_sc   = out + (size_t)BB*NKP*2 + (size_t)BB*NKP*128;  // BB*NKP

    hipMemsetAsync(d_ws, 0, 64, stream);   // zero cnt[] each launch (replay-safe)
    k_nms <<<NMSBLKS + JDBLKS, 256, 0, stream>>>(in, juncs, cnt, candK, sortK,
                                                 out_kp, out_desc, out_sc);
    k_rank<<<BB*32,            256, 0, stream>>>(cnt, candK, sortK);
    k_desc<<<512,              256, 0, stream>>>(in, sortK, out_kp, out_desc, out_sc);
}

// Round 6
// 37.743 us; speedup vs baseline: 4.1260x; 2.6231x over previous
//
#include <hip/hip_runtime.h>
#include <math.h>
#include <stdint.h>

#define BB 4
#define CC 129
#define HH 512
#define WW 512
#define HWSZ (HH*WW)
#define JJ 512
#define KK 1024
#define NKP (JJ+KK)
#define RAD 7
#define TS 32
#define HL (TS + 2*RAD)      // 46
#define TPB 256              // tiles per batch (16x16 of 32x32)
#define SLOTS 32             // max peaks per tile (geometry bound is 16; ties margin)
#define NL 2048              // max ranked candidates (expected n ~= 1165)
#define NMS_THRESH 0.99f
#define SENT 0xFF800000FFFFFFFFULL   // v=-inf, idx=~0 sentinel

// ws layout (bytes)
static const size_t OFF_TCNT  = 0;                       // BB*TPB ints = 4 KB
static const size_t OFF_TKEYS = 4096;                    // BB*TPB*SLOTS*8 = 256 KB

// K1: tiled 15x15 NMS (separable, in LDS). Each tile writes its own count +
// candidate slots: no global atomics, count overwritten every replay (no memset
// needed), candidate SET per tile is deterministic (LDS-atomic order isn't, but
// downstream rank-counting is order-invariant).
__global__ __launch_bounds__(256)
void k_nms(const float* __restrict__ in, int* __restrict__ tileCnt,
           uint64_t* __restrict__ tileKeys) {
    __shared__ float s[HL*HL];      // 2116 floats
    __shared__ float hm[HL*TS];     // 1472 floats
    __shared__ int tcnt;
    const int tid = threadIdx.x, blk = blockIdx.x;
    int b = blk >> 8, t = blk & 255;
    int ty = t >> 4, tx = t & 15;
    int by = ty*TS - RAD, bx = tx*TS - RAD;
    const float* heat = in + (size_t)b * CC * HWSZ;
    if (tid == 0) tcnt = 0;
    for (int i = tid; i < HL*HL; i += 256) {
        int r = i / HL, c = i - r*HL;
        int gy = by + r, gx = bx + c;
        s[i] = (gy >= 0 && gy < HH && gx >= 0 && gx < WW)
                 ? heat[gy*WW + gx] : -INFINITY;
    }
    __syncthreads();
    for (int i = tid; i < HL*TS; i += 256) {      // horizontal 15-max
        int r = i >> 5, c = i & 31;
        const float* sp = s + r*HL + c;
        float m = sp[0];
        #pragma unroll
        for (int k = 1; k < 15; ++k) m = fmaxf(m, sp[k]);
        hm[i] = m;
    }
    __syncthreads();
    uint64_t* tk = tileKeys + (size_t)blk * SLOTS;
    for (int i = tid; i < TS*TS; i += 256) {      // vertical 15-max + collect
        int r = i >> 5, c = i & 31;
        float v = s[(r+RAD)*HL + (c+RAD)];
        if (v > NMS_THRESH) {
            const float* hp = hm + r*TS + c;
            float m = hp[0];
            #pragma unroll
            for (int k = 1; k < 15; ++k) m = fmaxf(m, hp[k*TS]);
            if (v == m) {                          // exact fp equality, as ref
                int pos = atomicAdd(&tcnt, 1);     // LDS atomic, block-local
                if (pos < SLOTS) {
                    uint32_t idx = (uint32_t)((ty*TS + r)*WW + (tx*TS + c));
                    tk[pos] = ((uint64_t)__float_as_uint(v) << 32)
                            | (uint32_t)(~idx);
                }
            }
        }
    }
    __syncthreads();
    if (tid == 0) tileCnt[blk] = (tcnt < SLOTS) ? tcnt : SLOTS;
}

// K2: per block -> (a) 4 junction descriptors, (b) compact batch candidates to
// LDS (deterministic tile-major offsets via scan), (c) rank-count a 16-item
// chunk (rank = #{key_j > key_i}; keys distinct, so ranks are a permutation ->
// each output slot written exactly once, order-invariant => deterministic),
// (d) gather+normalize descriptors for its items, writing DIRECTLY to output
// slot `rank`. No sortK buffer, no third kernel.
__global__ __launch_bounds__(256)
void k_rankdesc(const float* __restrict__ in, const int* __restrict__ juncs,
                const int* __restrict__ tileCnt, const uint64_t* __restrict__ tileKeys,
                float* __restrict__ out_kp, float* __restrict__ out_desc,
                float* __restrict__ out_sc) {
    __shared__ uint64_t sk[NL];          // 16 KB
    __shared__ int sca[TPB], scb[TPB];   // scan ping-pong
    __shared__ int part[256];
    __shared__ float red[256];
    __shared__ uint64_t eKey[16];
    __shared__ int eRank[16];
    const int tid = threadIdx.x, blk = blockIdx.x;

    // ---- phase 0: junction descriptors (wave w -> junc kp blk*4 + w) ----
    {
        int w = tid >> 6, l = tid & 63;
        int j = blk*4 + w;                // 0..2047
        int jb = j >> 9, jk = j & 511;
        int kx = juncs[(jb*JJ + jk)*2 + 0];
        int ky = juncs[(jb*JJ + jk)*2 + 1];
        int fi = ky*WW + kx;
        const float* fp = in + (size_t)jb*CC*HWSZ + HWSZ + fi;
        float a0 = fp[(size_t)l*HWSZ];
        float a1 = fp[(size_t)(l + 64)*HWSZ];
        float sq = a0*a0 + a1*a1;
        for (int m = 1; m < 64; m <<= 1) sq += __shfl_xor(sq, m, 64);
        float nrm = fmaxf(sqrtf(sq), 1e-12f);
        int go = jb*NKP + jk;
        float* dp = out_desc + (size_t)go * 128;
        dp[l]      = a0 / nrm;
        dp[l + 64] = a1 / nrm;
        if (l == 0) {
            out_kp[2*go]     = (float)kx;
            out_kp[2*go + 1] = (float)ky;
            out_sc[go]       = 1.0f;
        }
    }

    // ---- phase 1: compact this batch's candidates into LDS ----
    int b = blk >> 7, chunk = blk & 127;
    int i0 = chunk * 16;
    int cnt_t = tileCnt[b*TPB + tid];    // tid in [0,256) == TPB
    sca[tid] = cnt_t;
    __syncthreads();
    int* src = sca; int* dst = scb;
    for (int off = 1; off < TPB; off <<= 1) {
        dst[tid] = src[tid] + ((tid >= off) ? src[tid - off] : 0);
        __syncthreads();
        int* tmp = src; src = dst; dst = tmp;
    }
    int off_t = src[tid] - cnt_t;        // exclusive offset, tile-major (deterministic)
    int n = src[TPB-1]; if (n > NL) n = NL;
    const uint64_t* tkb = tileKeys + (size_t)(b*TPB) * SLOTS;
    for (int j = 0; j < cnt_t; ++j) {
        int o = off_t + j;
        if (o < NL) sk[o] = tkb[(size_t)tid*SLOTS + j];
    }
    __syncthreads();

    // ---- phase 2: v0 = max candidate value (batch max, block-local) ----
    float mx = -INFINITY;
    for (int i = tid; i < n; i += 256)
        mx = fmaxf(mx, __uint_as_float((uint32_t)(sk[i] >> 32)));
    red[tid] = mx;
    __syncthreads();
    for (int s2 = 128; s2 > 0; s2 >>= 1) {
        if (tid < s2) red[tid] = fmaxf(red[tid], red[tid + s2]);
        __syncthreads();
    }
    float v0 = red[0];

    // ---- phase 3: rank-count chunk items (16 items, 16 j-subranges) ----
    {
        int it = tid & 15, sub = tid >> 4;
        int i = i0 + it;
        uint64_t key = (i < n) ? sk[i] : SENT;
        int jc = (n + 15) >> 4;
        int j0 = sub*jc, j1 = j0 + jc; if (j1 > n) j1 = n;
        int r = 0;
        for (int j = j0; j < j1; ++j) r += (sk[j] > key);
        part[tid] = r;                    // part[sub*16+it] == part[tid]
        __syncthreads();
        if (tid < 16) {
            int rank = 0;
            #pragma unroll
            for (int s2 = 0; s2 < 16; ++s2) rank += part[s2*16 + tid];
            int i_ = i0 + tid;
            if (i_ >= n) rank = i_;       // sentinel items: rank := index (only matters if n < KK)
            eKey[tid]  = (i_ < n) ? sk[i_] : SENT;
            eRank[tid] = rank;
        }
        __syncthreads();
    }

    // ---- phase 4: descriptor gather for surviving items (write to slot rank) ----
    {
        int hw = tid >> 5, l = tid & 31;
        for (int s2 = hw; s2 < 16; s2 += 8) {
            int rank = eRank[s2];
            if (rank < KK) {
                uint64_t key = eKey[s2];
                float v = __uint_as_float((uint32_t)(key >> 32));
                int rr = (int)(~(uint32_t)key);
                int kx = rr & (WW-1), ky = (rr >> 9) & (HH-1);
                float sc = v / v0;
                int fi = ky*WW + kx;
                const float* fp = in + (size_t)b*CC*HWSZ + HWSZ + fi;
                float a0 = fp[(size_t)(l      )*HWSZ];
                float a1 = fp[(size_t)(l + 32 )*HWSZ];
                float a2 = fp[(size_t)(l + 64 )*HWSZ];
                float a3 = fp[(size_t)(l + 96 )*HWSZ];
                float sq = a0*a0 + a1*a1 + a2*a2 + a3*a3;
                for (int m = 1; m < 32; m <<= 1) sq += __shfl_xor(sq, m, 32);
                float nrm = fmaxf(sqrtf(sq), 1e-12f);
                int go = b*NKP + JJ + rank;
                float* dp = out_desc + (size_t)go * 128;
                dp[l]      = a0 / nrm;
                dp[l + 32] = a1 / nrm;
                dp[l + 64] = a2 / nrm;
                dp[l + 96] = a3 / nrm;
                if (l == 0) {
                    out_kp[2*go]     = (float)kx;
                    out_kp[2*go + 1] = (float)ky;
                    out_sc[go]       = sc;
                }
            }
        }
    }
}

extern "C" void kernel_launch(void* const* d_in, const int* in_sizes, int n_in,
                              void* d_out, int out_size, void* d_ws, size_t ws_size,
                              hipStream_t stream) {
    const float* in  = (const float*)d_in[0];
    const int* juncs = (const int*)d_in[1];
    float* out       = (float*)d_out;

    char* ws = (char*)d_ws;
    int*      tileCnt  = (int*)(ws + OFF_TCNT);
    uint64_t* tileKeys = (uint64_t*)(ws + OFF_TKEYS);

    float* out_kp   = out;                                          // BB*NKP*2
    float* out_desc = out + (size_t)BB*NKP*2;                       // BB*NKP*128
    float* out_sc   = out + (size_t)BB*NKP*2 + (size_t)BB*NKP*128;  // BB*NKP

    k_nms     <<<BB*TPB, 256, 0, stream>>>(in, tileCnt, tileKeys);
    k_rankdesc<<<512,    256, 0, stream>>>(in, juncs, tileCnt, tileKeys,
                                           out_kp, out_desc, out_sc);
}